// Round 3
// baseline (831.377 us; speedup 1.0000x reference)
//
#include <hip/hip_runtime.h>
#include <hip/hip_bf16.h>

typedef short bf16x8 __attribute__((ext_vector_type(8)));
typedef float f32x4 __attribute__((ext_vector_type(4)));
typedef unsigned int u32;
typedef unsigned int u32x2 __attribute__((ext_vector_type(2)));

#define MFMA16 __builtin_amdgcn_mfma_f32_16x16x32_bf16
#define SCALE 0.17677669529663687f  // 1/sqrt(32)

// ws layout (bytes):
//   wqkv  bf16 [576][192]          @ 0        (221184)
//   wproj bf16 [192][192]          @ 221184   (73728)
//   biasar f32 [6][16][64][4]      @ 294912   (98304)
//   bq    f32  [576]               @ 393216   (2304)

__device__ __forceinline__ unsigned short f2b(float x) {
  u32 u = __float_as_uint(x);
  u = (u + 0x7FFFu + ((u >> 16) & 1u)) >> 16;
  return (unsigned short)u;
}
__device__ __forceinline__ u32 pk2(float a, float b) {
  __hip_bfloat162 h = __float22bfloat162_rn(float2{a, b});
  return *(u32*)&h;
}

// C-frag pair (a0 = regs for d/m block 0..15, a1 = block 16..31 of this 32-slice)
// -> A/B-frag bf16x8 via 2x v_permlane16_swap (VALU). The k-dim carries a fixed
// permutation pi (middle 8-blocks swapped); pi is identical for every operand
// produced by this helper, so it cancels inside MFMA dot products.
__device__ __forceinline__ bf16x8 xpose(f32x4 a0, f32x4 a1) {
  u32 s0 = pk2(a0[0], a0[1]);
  u32 s1 = pk2(a0[2], a0[3]);
  u32 s2 = pk2(a1[0], a1[1]);
  u32 s3 = pk2(a1[2], a1[3]);
  u32x2 r0 = __builtin_amdgcn_permlane16_swap(s0, s2, false, false);
  u32x2 r1 = __builtin_amdgcn_permlane16_swap(s1, s3, false, false);
  union {
    u32 w[4];
    bf16x8 v;
  } u;
  u.w[0] = r0[0];
  u.w[1] = r1[0];
  u.w[2] = r0[1];
  u.w[3] = r1[1];
  return u.v;
}

__global__ void prep_kernel(const float* __restrict__ qkv_w, const float* __restrict__ qkv_b,
                            const float* __restrict__ proj_w, const float* __restrict__ rpb,
                            unsigned short* __restrict__ wqkv, unsigned short* __restrict__ wproj,
                            float* __restrict__ biasar, float* __restrict__ bq) {
  int i0 = blockIdx.x * blockDim.x + threadIdx.x;
  int stride = gridDim.x * blockDim.x;
  for (int i = i0; i < 576 * 192; i += stride) {
    float v = qkv_w[i];
    if (i < 192 * 192) v *= SCALE;  // q rows are f < 192
    wqkv[i] = f2b(v);
  }
  for (int i = i0; i < 192 * 192; i += stride) wproj[i] = f2b(proj_w[i]);
  for (int i = i0; i < 576; i += stride) {
    float v = qkv_b[i];
    if (i < 192) v *= SCALE;
    bq[i] = v;
  }
  // bias pre-arranged in S^T C-fragment layout:
  // frag id = mt*4+nt; value at (lane,r): m = mt*16 + (lane>>4)*4 + r ; n = nt*16 + (lane&15)
  for (int i = i0; i < 6 * 16 * 64 * 4; i += stride) {
    int r = i & 3;
    int lane = (i >> 2) & 63;
    int fid = (i >> 8) & 15;
    int h = i >> 12;
    int mt = fid >> 2, nt = fid & 3;
    int m = mt * 16 + (lane >> 4) * 4 + r;
    int n = nt * 16 + (lane & 15);
    int idx = ((n >> 3) - (m >> 3) + 7) * 15 + ((n & 7) - (m & 7) + 7);
    biasar[i] = rpb[idx * 6 + h];
  }
}

// One block = one window. 6 waves, wave w = head w.
// LDS (24576 B): xs: x bf16 [64 tok][384B rows], 16B slots XOR-swizzled by (row&7).
// After attention, Os (bf16, same geometry) overlays xs. No per-wave scratch:
// all fragment transposes are in-register via permlane16_swap.
__global__ void __launch_bounds__(384, 5) win_attn(
    const float* __restrict__ x, const unsigned short* __restrict__ wqkv,
    const unsigned short* __restrict__ wproj, const float* __restrict__ biasar,
    const float* __restrict__ bq, const float* __restrict__ proj_b, float* __restrict__ out) {
  __shared__ __align__(16) char smem[24576];
  const int b = blockIdx.x;
  const int tid = threadIdx.x;
  const int w = tid >> 6;  // wave = head
  const int lane = tid & 63;
  const int g = lane >> 4;  // 16-lane group
  const int c = lane & 15;
  char* xs = smem;

  // ---------- stage full x -> bf16 swizzled LDS ----------
  {
    const float* xb = x + (size_t)b * 12288;
#pragma unroll
    for (int it = 0; it < 8; ++it) {
      int idx = tid + it * 384;  // float4 index in [0,3072)
      int tok = idx / 48, c4 = idx % 48;
      float4 v = *(const float4*)(xb + tok * 192 + c4 * 4);
      *(uint2*)(xs + tok * 384 + (((c4 >> 1) ^ (tok & 7)) << 4) + (c4 & 1) * 8) =
          make_uint2(pk2(v.x, v.y), pk2(v.z, v.w));
    }
  }
  __syncthreads();

#define XFRAG(tt, kt) \
  (*(const bf16x8*)(xs + ((tt) * 16 + c) * 384 + ((((kt) * 4 + g) ^ (c & 7)) << 4)))

  // ---------- Q pass ----------
  bf16x8 qb[4];
  {
    f32x4 acc[2][4];
#pragma unroll
    for (int dt = 0; dt < 2; ++dt)
#pragma unroll
      for (int tt = 0; tt < 4; ++tt) acc[dt][tt] = (f32x4)0.0f;
#pragma unroll
    for (int kt = 0; kt < 6; ++kt) {
      bf16x8 wf[2];
#pragma unroll
      for (int dt = 0; dt < 2; ++dt)
        wf[dt] = *(const bf16x8*)(wqkv + (size_t)(w * 32 + dt * 16 + c) * 192 + kt * 32 + 8 * g);
#pragma unroll
      for (int tt = 0; tt < 4; ++tt) {
        bf16x8 xf = XFRAG(tt, kt);
#pragma unroll
        for (int dt = 0; dt < 2; ++dt) acc[dt][tt] = MFMA16(wf[dt], xf, acc[dt][tt], 0, 0, 0);
      }
    }
#pragma unroll
    for (int dt = 0; dt < 2; ++dt)
#pragma unroll
      for (int r = 0; r < 4; ++r) {
        float bv = bq[w * 32 + dt * 16 + 4 * g + r];
#pragma unroll
        for (int tt = 0; tt < 4; ++tt) acc[dt][tt][r] += bv;
      }
#pragma unroll
    for (int nt = 0; nt < 4; ++nt) qb[nt] = xpose(acc[0][nt], acc[1][nt]);
  }

  // ---------- K pass ----------
  bf16x8 ka[4];
  {
    f32x4 acc[2][4];
#pragma unroll
    for (int dt = 0; dt < 2; ++dt)
#pragma unroll
      for (int tt = 0; tt < 4; ++tt) acc[dt][tt] = (f32x4)0.0f;
#pragma unroll
    for (int kt = 0; kt < 6; ++kt) {
      bf16x8 wf[2];
#pragma unroll
      for (int dt = 0; dt < 2; ++dt)
        wf[dt] =
            *(const bf16x8*)(wqkv + (size_t)(192 + w * 32 + dt * 16 + c) * 192 + kt * 32 + 8 * g);
#pragma unroll
      for (int tt = 0; tt < 4; ++tt) {
        bf16x8 xf = XFRAG(tt, kt);
#pragma unroll
        for (int dt = 0; dt < 2; ++dt) acc[dt][tt] = MFMA16(wf[dt], xf, acc[dt][tt], 0, 0, 0);
      }
    }
#pragma unroll
    for (int dt = 0; dt < 2; ++dt)
#pragma unroll
      for (int r = 0; r < 4; ++r) {
        float bv = bq[192 + w * 32 + dt * 16 + 4 * g + r];
#pragma unroll
        for (int tt = 0; tt < 4; ++tt) acc[dt][tt][r] += bv;
      }
#pragma unroll
    for (int mt = 0; mt < 4; ++mt) ka[mt] = xpose(acc[0][mt], acc[1][mt]);
  }

  // ---------- S in two n-halves: bias, softmax, pack P frags (all in-register) ----------
  bf16x8 pbf[2][4];
  float linv[4];
  const f32x4* bias4 = (const f32x4*)biasar;
#pragma unroll
  for (int h = 0; h < 2; ++h) {
    f32x4 s[4][2];
#pragma unroll
    for (int mt = 0; mt < 4; ++mt)
#pragma unroll
      for (int n2 = 0; n2 < 2; ++n2) {
        int nt = h * 2 + n2;
        f32x4 t = MFMA16(ka[mt], qb[nt], (f32x4)0.0f, 0, 0, 0);
        s[mt][n2] = t + bias4[(w * 16 + mt * 4 + nt) * 64 + lane];
      }
#pragma unroll
    for (int n2 = 0; n2 < 2; ++n2) {
      int nt = h * 2 + n2;
      float mx = -1e30f;
#pragma unroll
      for (int mt = 0; mt < 4; ++mt)
#pragma unroll
        for (int r = 0; r < 4; ++r) mx = fmaxf(mx, s[mt][n2][r]);
      mx = fmaxf(mx, __shfl_xor(mx, 16));
      mx = fmaxf(mx, __shfl_xor(mx, 32));
      float sum = 0.0f;
#pragma unroll
      for (int mt = 0; mt < 4; ++mt)
#pragma unroll
        for (int r = 0; r < 4; ++r) {
          float e = __expf(s[mt][n2][r] - mx);
          s[mt][n2][r] = e;
          sum += e;
        }
      sum += __shfl_xor(sum, 16);
      sum += __shfl_xor(sum, 32);
      linv[nt] = 1.0f / sum;
    }
#pragma unroll
    for (int n2 = 0; n2 < 2; ++n2) {
      pbf[0][h * 2 + n2] = xpose(s[0][n2], s[1][n2]);
      pbf[1][h * 2 + n2] = xpose(s[2][n2], s[3][n2]);
    }
  }

  // ---------- V pass ----------
  bf16x8 va[2][2];
  {
    f32x4 acc[4][2];
#pragma unroll
    for (int mt = 0; mt < 4; ++mt)
#pragma unroll
      for (int dt = 0; dt < 2; ++dt) acc[mt][dt] = (f32x4)0.0f;
#pragma unroll
    for (int kt = 0; kt < 6; ++kt) {
      bf16x8 wf[2];
#pragma unroll
      for (int dt = 0; dt < 2; ++dt)
        wf[dt] =
            *(const bf16x8*)(wqkv + (size_t)(384 + w * 32 + dt * 16 + c) * 192 + kt * 32 + 8 * g);
#pragma unroll
      for (int tt = 0; tt < 4; ++tt) {
        bf16x8 xf = XFRAG(tt, kt);
#pragma unroll
        for (int dt = 0; dt < 2; ++dt) acc[tt][dt] = MFMA16(xf, wf[dt], acc[tt][dt], 0, 0, 0);
      }
    }
#pragma unroll
    for (int dt = 0; dt < 2; ++dt) {
      float bv = bq[384 + w * 32 + dt * 16 + c];
#pragma unroll
      for (int mt = 0; mt < 4; ++mt)
#pragma unroll
        for (int r = 0; r < 4; ++r) acc[mt][dt][r] += bv;
    }
#pragma unroll
    for (int dt = 0; dt < 2; ++dt)
#pragma unroll
      for (int kh = 0; kh < 2; ++kh) va[dt][kh] = xpose(acc[2 * kh][dt], acc[2 * kh + 1][dt]);
  }

  // ---------- O^T = V^T @ P^T ----------
  f32x4 o[2][4];
#pragma unroll
  for (int dt = 0; dt < 2; ++dt)
#pragma unroll
    for (int nt = 0; nt < 4; ++nt) o[dt][nt] = (f32x4)0.0f;
#pragma unroll
  for (int mh = 0; mh < 2; ++mh)
#pragma unroll
    for (int nt = 0; nt < 4; ++nt)
#pragma unroll
      for (int dt = 0; dt < 2; ++dt) o[dt][nt] = MFMA16(va[dt][mh], pbf[mh][nt], o[dt][nt], 0, 0, 0);
#pragma unroll
  for (int dt = 0; dt < 2; ++dt)
#pragma unroll
    for (int nt = 0; nt < 4; ++nt)
#pragma unroll
      for (int r = 0; r < 4; ++r) o[dt][nt][r] *= linv[nt];

  // ---------- Os stage (token rows, overlays xs) ----------
  __syncthreads();
#pragma unroll
  for (int dt = 0; dt < 2; ++dt)
#pragma unroll
    for (int nt = 0; nt < 4; ++nt)
      *(uint2*)(xs + (nt * 16 + c) * 384 + (((w * 4 + dt * 2 + (g >> 1)) ^ (c & 7)) << 4) +
                (g & 1) * 8) = make_uint2(pk2(o[dt][nt][0], o[dt][nt][1]),
                                          pk2(o[dt][nt][2], o[dt][nt][3]));
  __syncthreads();

  // ---------- proj: out = Os @ proj_w^T + proj_b ----------
  f32x4 accP[4][2];
#pragma unroll
  for (int mt = 0; mt < 4; ++mt)
#pragma unroll
    for (int ft = 0; ft < 2; ++ft) accP[mt][ft] = (f32x4)0.0f;
#pragma unroll
  for (int kt = 0; kt < 6; ++kt) {
    bf16x8 wp[2];
#pragma unroll
    for (int ft = 0; ft < 2; ++ft)
      wp[ft] = *(const bf16x8*)(wproj + (size_t)(w * 32 + ft * 16 + c) * 192 + kt * 32 + 8 * g);
#pragma unroll
    for (int mt = 0; mt < 4; ++mt) {
      bf16x8 of = *(const bf16x8*)(xs + (mt * 16 + c) * 384 + (((kt * 4 + g) ^ (c & 7)) << 4));
#pragma unroll
      for (int ft = 0; ft < 2; ++ft) accP[mt][ft] = MFMA16(of, wp[ft], accP[mt][ft], 0, 0, 0);
    }
  }
  float pb0 = proj_b[w * 32 + c];
  float pb1 = proj_b[w * 32 + 16 + c];
  float* outb = out + (size_t)b * 12288;
#pragma unroll
  for (int mt = 0; mt < 4; ++mt)
#pragma unroll
    for (int ft = 0; ft < 2; ++ft) {
      float pbv = ft ? pb1 : pb0;
#pragma unroll
      for (int r = 0; r < 4; ++r)
        outb[(mt * 16 + 4 * g + r) * 192 + w * 32 + ft * 16 + c] = accP[mt][ft][r] + pbv;
    }
}

extern "C" void kernel_launch(void* const* d_in, const int* in_sizes, int n_in,
                              void* d_out, int out_size, void* d_ws, size_t ws_size,
                              hipStream_t stream) {
  const float* x = (const float*)d_in[0];
  const float* qkv_w = (const float*)d_in[1];
  const float* qkv_b = (const float*)d_in[2];
  const float* proj_w = (const float*)d_in[3];
  const float* proj_b = (const float*)d_in[4];
  const float* rpb = (const float*)d_in[5];
  char* ws = (char*)d_ws;
  unsigned short* wqkv = (unsigned short*)ws;
  unsigned short* wproj = (unsigned short*)(ws + 221184);
  float* biasar = (float*)(ws + 294912);
  float* bqv = (float*)(ws + 393216);

  prep_kernel<<<432, 256, 0, stream>>>(qkv_w, qkv_b, proj_w, rpb, wqkv, wproj, biasar, bqv);
  win_attn<<<4096, 384, 0, stream>>>(x, wqkv, wproj, biasar, bqv, proj_b, (float*)d_out);
}

// Round 4
// 323.224 us; speedup vs baseline: 2.5721x; 2.5721x over previous
//
#include <hip/hip_runtime.h>
#include <hip/hip_bf16.h>

typedef short bf16x8 __attribute__((ext_vector_type(8)));
typedef float f32x4 __attribute__((ext_vector_type(4)));
typedef unsigned int u32;
typedef unsigned int u32x2 __attribute__((ext_vector_type(2)));

#define MFMA16 __builtin_amdgcn_mfma_f32_16x16x32_bf16
#define SCALE 0.17677669529663687f  // 1/sqrt(32)

// ws layout (bytes):
//   wqkv  bf16 [576][192]          @ 0        (221184)
//   wproj bf16 [192][192]          @ 221184   (73728)
//   biasar f32 [6][16][64][4]      @ 294912   (98304)
//   bq    f32  [576]               @ 393216   (2304)

__device__ __forceinline__ unsigned short f2b(float x) {
  u32 u = __float_as_uint(x);
  u = (u + 0x7FFFu + ((u >> 16) & 1u)) >> 16;
  return (unsigned short)u;
}
__device__ __forceinline__ u32 pk2(float a, float b) {
  __hip_bfloat162 h = __float22bfloat162_rn(float2{a, b});
  return *(u32*)&h;
}

// C-frag pair (a0 = regs for d/m block 0..15, a1 = block 16..31 of this 32-slice)
// -> A/B-frag bf16x8 via 2x v_permlane16_swap (VALU). The k-dim carries a fixed
// permutation pi (middle 8-blocks swapped); pi is identical for every operand
// produced by this helper, so it cancels inside MFMA dot products.
__device__ __forceinline__ bf16x8 xpose(f32x4 a0, f32x4 a1) {
  u32 s0 = pk2(a0[0], a0[1]);
  u32 s1 = pk2(a0[2], a0[3]);
  u32 s2 = pk2(a1[0], a1[1]);
  u32 s3 = pk2(a1[2], a1[3]);
  u32x2 r0 = __builtin_amdgcn_permlane16_swap(s0, s2, false, false);
  u32x2 r1 = __builtin_amdgcn_permlane16_swap(s1, s3, false, false);
  union {
    u32 w[4];
    bf16x8 v;
  } u;
  u.w[0] = r0[0];
  u.w[1] = r1[0];
  u.w[2] = r0[1];
  u.w[3] = r1[1];
  return u.v;
}

__global__ void prep_kernel(const float* __restrict__ qkv_w, const float* __restrict__ qkv_b,
                            const float* __restrict__ proj_w, const float* __restrict__ rpb,
                            unsigned short* __restrict__ wqkv, unsigned short* __restrict__ wproj,
                            float* __restrict__ biasar, float* __restrict__ bq) {
  int i0 = blockIdx.x * blockDim.x + threadIdx.x;
  int stride = gridDim.x * blockDim.x;
  for (int i = i0; i < 576 * 192; i += stride) {
    float v = qkv_w[i];
    if (i < 192 * 192) v *= SCALE;  // q rows are f < 192
    wqkv[i] = f2b(v);
  }
  for (int i = i0; i < 192 * 192; i += stride) wproj[i] = f2b(proj_w[i]);
  for (int i = i0; i < 576; i += stride) {
    float v = qkv_b[i];
    if (i < 192) v *= SCALE;
    bq[i] = v;
  }
  // bias pre-arranged in S^T C-fragment layout:
  // frag id = mt*4+nt; value at (lane,r): m = mt*16 + (lane>>4)*4 + r ; n = nt*16 + (lane&15)
  for (int i = i0; i < 6 * 16 * 64 * 4; i += stride) {
    int r = i & 3;
    int lane = (i >> 2) & 63;
    int fid = (i >> 8) & 15;
    int h = i >> 12;
    int mt = fid >> 2, nt = fid & 3;
    int m = mt * 16 + (lane >> 4) * 4 + r;
    int n = nt * 16 + (lane & 15);
    int idx = ((n >> 3) - (m >> 3) + 7) * 15 + ((n & 7) - (m & 7) + 7);
    biasar[i] = rpb[idx * 6 + h];
  }
}

// One block = one window. 6 waves, wave w = head w.
// LDS (24576 B): xs: x bf16 [64 tok][384B rows], 16B slots XOR-swizzled by (row&7).
// After attention, Os (bf16, same geometry) overlays xs. No per-wave scratch:
// all fragment transposes are in-register via permlane16_swap.
// launch_bounds(384,3): cap ~170 VGPR -> no spill (the in-register design needs
// ~140-150 live regs); 2 blocks/CU = 12 waves. (384,5)'s 102-reg cap spilled
// ~3.2 GB of scratch traffic in round 3.
__global__ void __launch_bounds__(384, 3) win_attn(
    const float* __restrict__ x, const unsigned short* __restrict__ wqkv,
    const unsigned short* __restrict__ wproj, const float* __restrict__ biasar,
    const float* __restrict__ bq, const float* __restrict__ proj_b, float* __restrict__ out) {
  __shared__ __align__(16) char smem[24576];
  const int b = blockIdx.x;
  const int tid = threadIdx.x;
  const int w = tid >> 6;  // wave = head
  const int lane = tid & 63;
  const int g = lane >> 4;  // 16-lane group
  const int c = lane & 15;
  char* xs = smem;

  // ---------- stage full x -> bf16 swizzled LDS ----------
  {
    const float* xb = x + (size_t)b * 12288;
#pragma unroll
    for (int it = 0; it < 8; ++it) {
      int idx = tid + it * 384;  // float4 index in [0,3072)
      int tok = idx / 48, c4 = idx % 48;
      float4 v = *(const float4*)(xb + tok * 192 + c4 * 4);
      *(uint2*)(xs + tok * 384 + (((c4 >> 1) ^ (tok & 7)) << 4) + (c4 & 1) * 8) =
          make_uint2(pk2(v.x, v.y), pk2(v.z, v.w));
    }
  }
  __syncthreads();

#define XFRAG(tt, kt) \
  (*(const bf16x8*)(xs + ((tt) * 16 + c) * 384 + ((((kt) * 4 + g) ^ (c & 7)) << 4)))

  // ---------- Q pass ----------
  bf16x8 qb[4];
  {
    f32x4 acc[2][4];
#pragma unroll
    for (int dt = 0; dt < 2; ++dt)
#pragma unroll
      for (int tt = 0; tt < 4; ++tt) acc[dt][tt] = (f32x4)0.0f;
#pragma unroll
    for (int kt = 0; kt < 6; ++kt) {
      bf16x8 wf[2];
#pragma unroll
      for (int dt = 0; dt < 2; ++dt)
        wf[dt] = *(const bf16x8*)(wqkv + (size_t)(w * 32 + dt * 16 + c) * 192 + kt * 32 + 8 * g);
#pragma unroll
      for (int tt = 0; tt < 4; ++tt) {
        bf16x8 xf = XFRAG(tt, kt);
#pragma unroll
        for (int dt = 0; dt < 2; ++dt) acc[dt][tt] = MFMA16(wf[dt], xf, acc[dt][tt], 0, 0, 0);
      }
    }
#pragma unroll
    for (int dt = 0; dt < 2; ++dt)
#pragma unroll
      for (int r = 0; r < 4; ++r) {
        float bv = bq[w * 32 + dt * 16 + 4 * g + r];
#pragma unroll
        for (int tt = 0; tt < 4; ++tt) acc[dt][tt][r] += bv;
      }
#pragma unroll
    for (int nt = 0; nt < 4; ++nt) qb[nt] = xpose(acc[0][nt], acc[1][nt]);
  }

  // ---------- K pass ----------
  bf16x8 ka[4];
  {
    f32x4 acc[2][4];
#pragma unroll
    for (int dt = 0; dt < 2; ++dt)
#pragma unroll
      for (int tt = 0; tt < 4; ++tt) acc[dt][tt] = (f32x4)0.0f;
#pragma unroll
    for (int kt = 0; kt < 6; ++kt) {
      bf16x8 wf[2];
#pragma unroll
      for (int dt = 0; dt < 2; ++dt)
        wf[dt] =
            *(const bf16x8*)(wqkv + (size_t)(192 + w * 32 + dt * 16 + c) * 192 + kt * 32 + 8 * g);
#pragma unroll
      for (int tt = 0; tt < 4; ++tt) {
        bf16x8 xf = XFRAG(tt, kt);
#pragma unroll
        for (int dt = 0; dt < 2; ++dt) acc[dt][tt] = MFMA16(wf[dt], xf, acc[dt][tt], 0, 0, 0);
      }
    }
#pragma unroll
    for (int dt = 0; dt < 2; ++dt)
#pragma unroll
      for (int r = 0; r < 4; ++r) {
        float bv = bq[192 + w * 32 + dt * 16 + 4 * g + r];
#pragma unroll
        for (int tt = 0; tt < 4; ++tt) acc[dt][tt][r] += bv;
      }
#pragma unroll
    for (int mt = 0; mt < 4; ++mt) ka[mt] = xpose(acc[0][mt], acc[1][mt]);
  }

  // ---------- S in two n-halves: bias, softmax, pack P frags (all in-register) ----------
  bf16x8 pbf[2][4];
  float linv[4];
  const f32x4* bias4 = (const f32x4*)biasar;
#pragma unroll
  for (int h = 0; h < 2; ++h) {
    f32x4 s[4][2];
#pragma unroll
    for (int mt = 0; mt < 4; ++mt)
#pragma unroll
      for (int n2 = 0; n2 < 2; ++n2) {
        int nt = h * 2 + n2;
        f32x4 t = MFMA16(ka[mt], qb[nt], (f32x4)0.0f, 0, 0, 0);
        s[mt][n2] = t + bias4[(w * 16 + mt * 4 + nt) * 64 + lane];
      }
#pragma unroll
    for (int n2 = 0; n2 < 2; ++n2) {
      int nt = h * 2 + n2;
      float mx = -1e30f;
#pragma unroll
      for (int mt = 0; mt < 4; ++mt)
#pragma unroll
        for (int r = 0; r < 4; ++r) mx = fmaxf(mx, s[mt][n2][r]);
      mx = fmaxf(mx, __shfl_xor(mx, 16));
      mx = fmaxf(mx, __shfl_xor(mx, 32));
      float sum = 0.0f;
#pragma unroll
      for (int mt = 0; mt < 4; ++mt)
#pragma unroll
        for (int r = 0; r < 4; ++r) {
          float e = __expf(s[mt][n2][r] - mx);
          s[mt][n2][r] = e;
          sum += e;
        }
      sum += __shfl_xor(sum, 16);
      sum += __shfl_xor(sum, 32);
      linv[nt] = 1.0f / sum;
    }
#pragma unroll
    for (int n2 = 0; n2 < 2; ++n2) {
      pbf[0][h * 2 + n2] = xpose(s[0][n2], s[1][n2]);
      pbf[1][h * 2 + n2] = xpose(s[2][n2], s[3][n2]);
    }
  }

  // ---------- V pass ----------
  bf16x8 va[2][2];
  {
    f32x4 acc[4][2];
#pragma unroll
    for (int mt = 0; mt < 4; ++mt)
#pragma unroll
      for (int dt = 0; dt < 2; ++dt) acc[mt][dt] = (f32x4)0.0f;
#pragma unroll
    for (int kt = 0; kt < 6; ++kt) {
      bf16x8 wf[2];
#pragma unroll
      for (int dt = 0; dt < 2; ++dt)
        wf[dt] =
            *(const bf16x8*)(wqkv + (size_t)(384 + w * 32 + dt * 16 + c) * 192 + kt * 32 + 8 * g);
#pragma unroll
      for (int tt = 0; tt < 4; ++tt) {
        bf16x8 xf = XFRAG(tt, kt);
#pragma unroll
        for (int dt = 0; dt < 2; ++dt) acc[tt][dt] = MFMA16(xf, wf[dt], acc[tt][dt], 0, 0, 0);
      }
    }
#pragma unroll
    for (int dt = 0; dt < 2; ++dt) {
      float bv = bq[384 + w * 32 + dt * 16 + c];
#pragma unroll
      for (int mt = 0; mt < 4; ++mt)
#pragma unroll
        for (int r = 0; r < 4; ++r) acc[mt][dt][r] += bv;
    }
#pragma unroll
    for (int dt = 0; dt < 2; ++dt)
#pragma unroll
      for (int kh = 0; kh < 2; ++kh) va[dt][kh] = xpose(acc[2 * kh][dt], acc[2 * kh + 1][dt]);
  }

  // ---------- O^T = V^T @ P^T ----------
  f32x4 o[2][4];
#pragma unroll
  for (int dt = 0; dt < 2; ++dt)
#pragma unroll
    for (int nt = 0; nt < 4; ++nt) o[dt][nt] = (f32x4)0.0f;
#pragma unroll
  for (int mh = 0; mh < 2; ++mh)
#pragma unroll
    for (int nt = 0; nt < 4; ++nt)
#pragma unroll
      for (int dt = 0; dt < 2; ++dt) o[dt][nt] = MFMA16(va[dt][mh], pbf[mh][nt], o[dt][nt], 0, 0, 0);
#pragma unroll
  for (int dt = 0; dt < 2; ++dt)
#pragma unroll
    for (int nt = 0; nt < 4; ++nt)
#pragma unroll
      for (int r = 0; r < 4; ++r) o[dt][nt][r] *= linv[nt];

  // ---------- Os stage (token rows, overlays xs) ----------
  __syncthreads();
#pragma unroll
  for (int dt = 0; dt < 2; ++dt)
#pragma unroll
    for (int nt = 0; nt < 4; ++nt)
      *(uint2*)(xs + (nt * 16 + c) * 384 + (((w * 4 + dt * 2 + (g >> 1)) ^ (c & 7)) << 4) +
                (g & 1) * 8) = make_uint2(pk2(o[dt][nt][0], o[dt][nt][1]),
                                          pk2(o[dt][nt][2], o[dt][nt][3]));
  __syncthreads();

  // ---------- proj: out = Os @ proj_w^T + proj_b ----------
  f32x4 accP[4][2];
#pragma unroll
  for (int mt = 0; mt < 4; ++mt)
#pragma unroll
    for (int ft = 0; ft < 2; ++ft) accP[mt][ft] = (f32x4)0.0f;
#pragma unroll
  for (int kt = 0; kt < 6; ++kt) {
    bf16x8 wp[2];
#pragma unroll
    for (int ft = 0; ft < 2; ++ft)
      wp[ft] = *(const bf16x8*)(wproj + (size_t)(w * 32 + ft * 16 + c) * 192 + kt * 32 + 8 * g);
#pragma unroll
    for (int mt = 0; mt < 4; ++mt) {
      bf16x8 of = *(const bf16x8*)(xs + (mt * 16 + c) * 384 + (((kt * 4 + g) ^ (c & 7)) << 4));
#pragma unroll
      for (int ft = 0; ft < 2; ++ft) accP[mt][ft] = MFMA16(of, wp[ft], accP[mt][ft], 0, 0, 0);
    }
  }
  float pb0 = proj_b[w * 32 + c];
  float pb1 = proj_b[w * 32 + 16 + c];
  float* outb = out + (size_t)b * 12288;
#pragma unroll
  for (int mt = 0; mt < 4; ++mt)
#pragma unroll
    for (int ft = 0; ft < 2; ++ft) {
      float pbv = ft ? pb1 : pb0;
#pragma unroll
      for (int r = 0; r < 4; ++r)
        outb[(mt * 16 + 4 * g + r) * 192 + w * 32 + ft * 16 + c] = accP[mt][ft][r] + pbv;
    }
}

extern "C" void kernel_launch(void* const* d_in, const int* in_sizes, int n_in,
                              void* d_out, int out_size, void* d_ws, size_t ws_size,
                              hipStream_t stream) {
  const float* x = (const float*)d_in[0];
  const float* qkv_w = (const float*)d_in[1];
  const float* qkv_b = (const float*)d_in[2];
  const float* proj_w = (const float*)d_in[3];
  const float* proj_b = (const float*)d_in[4];
  const float* rpb = (const float*)d_in[5];
  char* ws = (char*)d_ws;
  unsigned short* wqkv = (unsigned short*)ws;
  unsigned short* wproj = (unsigned short*)(ws + 221184);
  float* biasar = (float*)(ws + 294912);
  float* bqv = (float*)(ws + 393216);

  prep_kernel<<<432, 256, 0, stream>>>(qkv_w, qkv_b, proj_w, rpb, wqkv, wproj, biasar, bqv);
  win_attn<<<4096, 384, 0, stream>>>(x, wqkv, wproj, biasar, bqv, proj_b, (float*)d_out);
}